// Round 1
// baseline (254.239 us; speedup 1.0000x reference)
//
#include <hip/hip_runtime.h>
#include <hip/hip_bf16.h>
#include <stdint.h>

#define B_   4
#define CIN  32
#define COUT 32
#define NV   163842
#define K7   7

typedef short bf16x8 __attribute__((ext_vector_type(8)));
typedef float f32x4  __attribute__((ext_vector_type(4)));

__device__ inline uint16_t f2bf(float f) {
    uint32_t u = __float_as_uint(f);
    uint32_t r = (u + 0x7FFFu + ((u >> 16) & 1u)) >> 16;
    return (uint16_t)r;
}

// --- Kernel A: W (32 x 224) f32 -> bf16 ---------------------------------
__global__ void k_convw(const float* __restrict__ W, uint16_t* __restrict__ Wb) {
    int i = blockIdx.x * 256 + threadIdx.x;
    if (i < COUT * K7 * CIN) Wb[i] = f2bf(W[i]);
}

// --- Kernel B: x (B, 32, N) f32 -> xt (B, N, 32) bf16 -------------------
// Reads coalesced along N (fixed channel per instruction); each thread
// emits its vertex's 64-B bf16 row as 4x 16-B stores.
__global__ void k_transpose(const float* __restrict__ x, uint16_t* __restrict__ xt) {
    int v = blockIdx.x * 256 + threadIdx.x;
    int b = blockIdx.y;
    if (v >= NV) return;
    const float* xb = x + (size_t)b * CIN * NV;
    uint16_t* row = xt + ((size_t)b * NV + v) * CIN;
    #pragma unroll
    for (int q = 0; q < 4; ++q) {
        bf16x8 pk;
        #pragma unroll
        for (int i = 0; i < 8; ++i) {
            float f = xb[(size_t)(q * 8 + i) * NV + v];
            ((uint16_t*)&pk)[i] = f2bf(f);
        }
        *(bf16x8*)(row + q * 8) = pk;
    }
}

// --- Kernel C: gather + MFMA ---------------------------------------------
// Per wave: 16 vertices. A = W chunk (o x k), B = gathered X (k x vertex).
// D[o][v]: col = lane&15 = vertex, rows = (lane>>4)*4 + reg.
__global__ __launch_bounds__(256) void k_main(const uint16_t* __restrict__ xt,
                                              const uint16_t* __restrict__ Wb,
                                              const float* __restrict__ bias,
                                              const int* __restrict__ neigh,
                                              float* __restrict__ out) {
    const int tid  = threadIdx.x;
    const int lane = tid & 63;
    const int wv   = tid >> 6;                  // wave 0..3
    const int b    = blockIdx.y;
    const int vb   = blockIdx.x * 64 + wv * 16; // this wave's 16-vertex tile
    const int l15  = lane & 15;
    const int g    = lane >> 4;                 // 0..3 (k-group)
    const int v    = vb + l15;
    const int vv   = (v < NV) ? v : (NV - 1);

    // Preload W fragments: 2 o-tiles x 7 neighbor-chunks (16B each)
    bf16x8 wf[2][K7];
    #pragma unroll
    for (int t = 0; t < 2; ++t)
        #pragma unroll
        for (int j = 0; j < K7; ++j)
            wf[t][j] = *(const bf16x8*)(Wb + (size_t)(t * 16 + l15) * (K7 * CIN) + j * CIN + g * 8);

    // Neighbor indices for this lane's vertex
    int nidx[K7];
    #pragma unroll
    for (int j = 0; j < K7; ++j) nidx[j] = neigh[(size_t)vv * K7 + j];

    // Gather: one 16-B load per lane per neighbor (8 contiguous bf16 channels)
    const uint16_t* xb = xt + (size_t)b * NV * CIN;
    bf16x8 xf[K7];
    #pragma unroll
    for (int j = 0; j < K7; ++j)
        xf[j] = *(const bf16x8*)(xb + (size_t)nidx[j] * CIN + g * 8);

    f32x4 acc0 = {0.f, 0.f, 0.f, 0.f};
    f32x4 acc1 = {0.f, 0.f, 0.f, 0.f};
    #pragma unroll
    for (int j = 0; j < K7; ++j) {
        acc0 = __builtin_amdgcn_mfma_f32_16x16x32_bf16(wf[0][j], xf[j], acc0, 0, 0, 0);
        acc1 = __builtin_amdgcn_mfma_f32_16x16x32_bf16(wf[1][j], xf[j], acc1, 0, 0, 0);
    }

    if (v < NV) {
        float* ob = out + (size_t)b * COUT * NV + v;
        #pragma unroll
        for (int r = 0; r < 4; ++r) {
            int o0 = g * 4 + r;
            ob[(size_t)o0 * NV] = acc0[r] + bias[o0];
            int o1 = 16 + g * 4 + r;
            ob[(size_t)o1 * NV] = acc1[r] + bias[o1];
        }
    }
}

extern "C" void kernel_launch(void* const* d_in, const int* in_sizes, int n_in,
                              void* d_out, int out_size, void* d_ws, size_t ws_size,
                              hipStream_t stream) {
    const float* x     = (const float*)d_in[0];
    const float* W     = (const float*)d_in[1];
    const float* bias  = (const float*)d_in[2];
    const int*   neigh = (const int*)d_in[3];
    float* out = (float*)d_out;

    uint16_t* xt = (uint16_t*)d_ws;                       // B*N*32 bf16 = 41.9 MB
    uint16_t* Wb = xt + (size_t)B_ * NV * CIN;            // 7168 bf16

    k_convw<<<(COUT * K7 * CIN + 255) / 256, 256, 0, stream>>>(W, Wb);

    dim3 g1((NV + 255) / 256, B_);
    k_transpose<<<g1, 256, 0, stream>>>(x, xt);

    dim3 g2((NV + 63) / 64, B_);
    k_main<<<g2, 256, 0, stream>>>(xt, Wb, bias, neigh, out);
}

// Round 2
// 244.184 us; speedup vs baseline: 1.0412x; 1.0412x over previous
//
#include <hip/hip_runtime.h>
#include <hip/hip_bf16.h>
#include <stdint.h>

#define B_   4
#define CIN  32
#define COUT 32
#define NV   163842
#define K7   7

typedef short bf16x8 __attribute__((ext_vector_type(8)));
typedef float f32x4  __attribute__((ext_vector_type(4)));

__device__ inline uint16_t f2bf(float f) {
    uint32_t u = __float_as_uint(f);
    uint32_t r = (u + 0x7FFFu + ((u >> 16) & 1u)) >> 16;
    return (uint16_t)r;
}

// --- Kernel A: W (32 x 224) f32 -> bf16 ---------------------------------
__global__ void k_convw(const float* __restrict__ W, uint16_t* __restrict__ Wb) {
    int i = blockIdx.x * 256 + threadIdx.x;
    if (i < COUT * K7 * CIN) Wb[i] = f2bf(W[i]);
}

// --- Kernel B: x (B, 32, N) f32 -> xt (N, B, 32) bf16 (batch-interleaved)
// One thread = one (vertex, batch): 32 coalesced channel reads, one 64-B
// contiguous packed store inside the vertex's 256-B row.
__global__ void k_transpose(const float* __restrict__ x, uint16_t* __restrict__ xt) {
    int v = blockIdx.x * 256 + threadIdx.x;
    int b = blockIdx.y;
    if (v >= NV) return;
    const float* xb = x + (size_t)b * CIN * NV;
    uint16_t* row = xt + (size_t)v * (B_ * CIN) + b * CIN;
    #pragma unroll
    for (int q = 0; q < 4; ++q) {
        bf16x8 pk;
        #pragma unroll
        for (int i = 0; i < 8; ++i) {
            float f = xb[(size_t)(q * 8 + i) * NV + v];
            ((uint16_t*)&pk)[i] = f2bf(f);
        }
        *(bf16x8*)(row + q * 8) = pk;
    }
}

// --- Kernel C: gather + MFMA, all 4 batches per wave ---------------------
// Per wave: 16 vertices x 4 batches. A = W chunk (o x k), B = gathered X.
// Each neighbor gather consumes a full 256-B row (all batches).
__global__ __launch_bounds__(256) void k_main(const uint16_t* __restrict__ xt,
                                              const uint16_t* __restrict__ Wb,
                                              const float* __restrict__ bias,
                                              const int* __restrict__ neigh,
                                              float* __restrict__ out) {
    const int tid  = threadIdx.x;
    const int lane = tid & 63;
    const int wv   = tid >> 6;                  // wave 0..3
    const int vb   = blockIdx.x * 64 + wv * 16; // this wave's 16-vertex tile
    const int l15  = lane & 15;
    const int g    = lane >> 4;                 // 0..3 (k-group)
    const int v    = vb + l15;
    const int vv   = (v < NV) ? v : (NV - 1);

    // Preload W fragments: 2 o-tiles x 7 neighbor-chunks (16B each)
    bf16x8 wf[2][K7];
    #pragma unroll
    for (int t = 0; t < 2; ++t)
        #pragma unroll
        for (int j = 0; j < K7; ++j)
            wf[t][j] = *(const bf16x8*)(Wb + (size_t)(t * 16 + l15) * (K7 * CIN) + j * CIN + g * 8);

    // Neighbor indices for this lane's vertex (loaded ONCE for all batches)
    int nidx[K7];
    #pragma unroll
    for (int j = 0; j < K7; ++j) nidx[j] = neigh[(size_t)vv * K7 + j];

    f32x4 acc[B_][2];
    #pragma unroll
    for (int b = 0; b < B_; ++b) {
        acc[b][0] = (f32x4){0.f, 0.f, 0.f, 0.f};
        acc[b][1] = (f32x4){0.f, 0.f, 0.f, 0.f};
    }

    #pragma unroll
    for (int j = 0; j < K7; ++j) {
        const uint16_t* row = xt + (size_t)nidx[j] * (B_ * CIN);
        bf16x8 xf[B_];
        #pragma unroll
        for (int b = 0; b < B_; ++b)
            xf[b] = *(const bf16x8*)(row + b * CIN + g * 8);
        #pragma unroll
        for (int b = 0; b < B_; ++b) {
            acc[b][0] = __builtin_amdgcn_mfma_f32_16x16x32_bf16(wf[0][j], xf[b], acc[b][0], 0, 0, 0);
            acc[b][1] = __builtin_amdgcn_mfma_f32_16x16x32_bf16(wf[1][j], xf[b], acc[b][1], 0, 0, 0);
        }
    }

    if (v < NV) {
        f32x4 bia0 = *(const f32x4*)(bias + g * 4);
        f32x4 bia1 = *(const f32x4*)(bias + 16 + g * 4);
        #pragma unroll
        for (int b = 0; b < B_; ++b) {
            float* ob = out + (size_t)b * COUT * NV + v;
            #pragma unroll
            for (int r = 0; r < 4; ++r) {
                int o0 = g * 4 + r;
                ob[(size_t)o0 * NV] = acc[b][0][r] + bia0[r];
                int o1 = 16 + g * 4 + r;
                ob[(size_t)o1 * NV] = acc[b][1][r] + bia1[r];
            }
        }
    }
}

extern "C" void kernel_launch(void* const* d_in, const int* in_sizes, int n_in,
                              void* d_out, int out_size, void* d_ws, size_t ws_size,
                              hipStream_t stream) {
    const float* x     = (const float*)d_in[0];
    const float* W     = (const float*)d_in[1];
    const float* bias  = (const float*)d_in[2];
    const int*   neigh = (const int*)d_in[3];
    float* out = (float*)d_out;

    uint16_t* xt = (uint16_t*)d_ws;                       // NV*B*32 bf16 = 41.9 MB
    uint16_t* Wb = xt + (size_t)NV * B_ * CIN;            // 7168 bf16

    k_convw<<<(COUT * K7 * CIN + 255) / 256, 256, 0, stream>>>(W, Wb);

    dim3 g1((NV + 255) / 256, B_);
    k_transpose<<<g1, 256, 0, stream>>>(x, xt);

    dim3 g2((NV + 63) / 64, 1);
    k_main<<<g2, 256, 0, stream>>>(xt, Wb, bias, neigh, out);
}

// Round 3
// 237.041 us; speedup vs baseline: 1.0726x; 1.0301x over previous
//
#include <hip/hip_runtime.h>
#include <hip/hip_bf16.h>
#include <stdint.h>

#define B_   4
#define CIN  32
#define COUT 32
#define NV   163842
#define K7   7

typedef short bf16x8 __attribute__((ext_vector_type(8)));
typedef float f32x4  __attribute__((ext_vector_type(4)));

__device__ inline uint16_t f2bf(float f) {
    uint32_t u = __float_as_uint(f);
    uint32_t r = (u + 0x7FFFu + ((u >> 16) & 1u)) >> 16;
    return (uint16_t)r;
}

// --- Kernel A: W (32 x 224) f32 -> bf16 ---------------------------------
__global__ void k_convw(const float* __restrict__ W, uint16_t* __restrict__ Wb) {
    int i = blockIdx.x * 256 + threadIdx.x;
    if (i < COUT * K7 * CIN) Wb[i] = f2bf(W[i]);
}

// --- Kernel B: x (B, 32, N) f32 -> xt (N, B, 32) bf16, LDS-staged --------
// Phase 1: wave b reads channel planes coalesced (256B/instr), packs bf16,
// stages into padded LDS rows. Phase 2: waves write 1KB fully contiguous.
__global__ __launch_bounds__(256) void k_transpose(const float* __restrict__ x,
                                                   uint16_t* __restrict__ xt) {
    __shared__ uint16_t lds[64 * 132];          // 64 rows x 264B (256 + 8 pad)
    const int v0 = blockIdx.x * 64;
    const int b  = threadIdx.x >> 6;            // wave = batch
    const int vl = threadIdx.x & 63;            // lane = vertex
    const int v  = v0 + vl;

    if (v < NV) {
        const float* xb = x + (size_t)b * CIN * NV + v;
        #pragma unroll
        for (int q = 0; q < 4; ++q) {
            bf16x8 pk;
            #pragma unroll
            for (int i = 0; i < 8; ++i)
                ((uint16_t*)&pk)[i] = f2bf(xb[(size_t)(q * 8 + i) * NV]);
            *(bf16x8*)&lds[vl * 132 + b * 32 + q * 8] = pk;
        }
    }
    __syncthreads();

    const size_t lim = ((size_t)(NV - v0)) * 256;   // valid bytes in this tile
    uint16_t* dst = xt + (size_t)v0 * 128;          // v0*256B in shorts
    const int tid = threadIdx.x;
    #pragma unroll
    for (int s = 0; s < 4; ++s) {
        const int f = s * 4096 + tid * 16;          // byte offset in 16KB tile
        if ((size_t)f < lim) {
            const int row = f >> 8;
            const int w   = f & 255;
            bf16x8 d = *(bf16x8*)&lds[row * 132 + (w >> 1)];
            *(bf16x8*)(dst + (f >> 1)) = d;
        }
    }
}

// --- Kernel C: gather (coalesced, via per-wave LDS) + MFMA ---------------
// Gather role: lane l fetches row nidx[l>>2], bytes (l&3)*16 + i*64 --
// each quad covers 64B contiguous of one row. MFMA role reads B-frags
// from the wave-private LDS buffer (2-deep pipeline over neighbors).
#define MFMA_BF16 __builtin_amdgcn_mfma_f32_16x16x32_bf16

__global__ __launch_bounds__(256) void k_main(const uint16_t* __restrict__ xt,
                                              const uint16_t* __restrict__ Wb,
                                              const float* __restrict__ bias,
                                              const int* __restrict__ neigh,
                                              float* __restrict__ out) {
    __shared__ uint16_t lds[4][2][16 * 132];    // wave-private dbuf: 16 rows x 264B
    const int tid  = threadIdx.x;
    const int lane = tid & 63;
    const int wv   = tid >> 6;
    const int vb   = blockIdx.x * 64 + wv * 16;
    const int l15  = lane & 15;
    const int g    = lane >> 4;                 // k-group 0..3
    const int v    = vb + l15;
    // gather role
    const int gr   = lane >> 2;                 // row 0..15 this lane stages
    const int gc   = lane & 3;                  // 16B chunk selector
    const int gv   = vb + gr;
    const int gvv  = (gv < NV) ? gv : (NV - 1);

    // W fragments: 2 o-tiles x 7 neighbor chunks
    bf16x8 wf[2][K7];
    #pragma unroll
    for (int t = 0; t < 2; ++t)
        #pragma unroll
        for (int j = 0; j < K7; ++j)
            wf[t][j] = *(const bf16x8*)(Wb + (size_t)(t * 16 + l15) * (K7 * CIN) + j * CIN + g * 8);

    int nidxg[K7];
    #pragma unroll
    for (int j = 0; j < K7; ++j) nidxg[j] = neigh[(size_t)gvv * K7 + j];

    f32x4 acc[B_][2];
    #pragma unroll
    for (int b = 0; b < B_; ++b) {
        acc[b][0] = (f32x4){0.f, 0.f, 0.f, 0.f};
        acc[b][1] = (f32x4){0.f, 0.f, 0.f, 0.f};
    }

    const char* xtb = (const char*)xt;
    f32x4 ra0, ra1, ra2, ra3, rb0, rb1, rb2, rb3;

#define ISSUE(R0, R1, R2, R3, j) { \
    const char* _s = xtb + (size_t)nidxg[j] * 256 + gc * 16; \
    R0 = *(const f32x4*)(_s);       R1 = *(const f32x4*)(_s + 64); \
    R2 = *(const f32x4*)(_s + 128); R3 = *(const f32x4*)(_s + 192); }

#define WRITE(R0, R1, R2, R3, BUF) { \
    uint16_t* _d = &lds[wv][BUF][gr * 132 + gc * 8]; \
    *(f32x4*)(_d)      = R0; *(f32x4*)(_d + 32) = R1; \
    *(f32x4*)(_d + 64) = R2; *(f32x4*)(_d + 96) = R3; }

#define RM(BUF, j) { \
    const uint16_t* _r = &lds[wv][BUF][l15 * 132 + g * 8]; \
    bf16x8 xf0 = *(const bf16x8*)(_r); \
    bf16x8 xf1 = *(const bf16x8*)(_r + 32); \
    bf16x8 xf2 = *(const bf16x8*)(_r + 64); \
    bf16x8 xf3 = *(const bf16x8*)(_r + 96); \
    acc[0][0] = MFMA_BF16(wf[0][j], xf0, acc[0][0], 0, 0, 0); \
    acc[0][1] = MFMA_BF16(wf[1][j], xf0, acc[0][1], 0, 0, 0); \
    acc[1][0] = MFMA_BF16(wf[0][j], xf1, acc[1][0], 0, 0, 0); \
    acc[1][1] = MFMA_BF16(wf[1][j], xf1, acc[1][1], 0, 0, 0); \
    acc[2][0] = MFMA_BF16(wf[0][j], xf2, acc[2][0], 0, 0, 0); \
    acc[2][1] = MFMA_BF16(wf[1][j], xf2, acc[2][1], 0, 0, 0); \
    acc[3][0] = MFMA_BF16(wf[0][j], xf3, acc[3][0], 0, 0, 0); \
    acc[3][1] = MFMA_BF16(wf[1][j], xf3, acc[3][1], 0, 0, 0); }

    // 2-deep pipeline over the 7 neighbors (wave-private buffers, no barriers)
    ISSUE(ra0, ra1, ra2, ra3, 0);
    ISSUE(rb0, rb1, rb2, rb3, 1); WRITE(ra0, ra1, ra2, ra3, 0); RM(0, 0);
    ISSUE(ra0, ra1, ra2, ra3, 2); WRITE(rb0, rb1, rb2, rb3, 1); RM(1, 1);
    ISSUE(rb0, rb1, rb2, rb3, 3); WRITE(ra0, ra1, ra2, ra3, 0); RM(0, 2);
    ISSUE(ra0, ra1, ra2, ra3, 4); WRITE(rb0, rb1, rb2, rb3, 1); RM(1, 3);
    ISSUE(rb0, rb1, rb2, rb3, 5); WRITE(ra0, ra1, ra2, ra3, 0); RM(0, 4);
    ISSUE(ra0, ra1, ra2, ra3, 6); WRITE(rb0, rb1, rb2, rb3, 1); RM(1, 5);
                                  WRITE(ra0, ra1, ra2, ra3, 0); RM(0, 6);

    if (v < NV) {
        f32x4 bia0 = *(const f32x4*)(bias + g * 4);
        f32x4 bia1 = *(const f32x4*)(bias + 16 + g * 4);
        #pragma unroll
        for (int b = 0; b < B_; ++b) {
            float* ob = out + (size_t)b * COUT * NV + v;
            #pragma unroll
            for (int r = 0; r < 4; ++r) {
                int o0 = g * 4 + r;
                ob[(size_t)o0 * NV] = acc[b][0][r] + bia0[r];
                int o1 = 16 + g * 4 + r;
                ob[(size_t)o1 * NV] = acc[b][1][r] + bia1[r];
            }
        }
    }
}

extern "C" void kernel_launch(void* const* d_in, const int* in_sizes, int n_in,
                              void* d_out, int out_size, void* d_ws, size_t ws_size,
                              hipStream_t stream) {
    const float* x     = (const float*)d_in[0];
    const float* W     = (const float*)d_in[1];
    const float* bias  = (const float*)d_in[2];
    const int*   neigh = (const int*)d_in[3];
    float* out = (float*)d_out;

    uint16_t* xt = (uint16_t*)d_ws;                       // NV*B*32 bf16 = 41.9 MB
    uint16_t* Wb = xt + (size_t)NV * B_ * CIN;            // 7168 bf16

    k_convw<<<(COUT * K7 * CIN + 255) / 256, 256, 0, stream>>>(W, Wb);

    dim3 g1((NV + 63) / 64, 1);
    k_transpose<<<g1, 256, 0, stream>>>(x, xt);

    dim3 g2((NV + 63) / 64, 1);
    k_main<<<g2, 256, 0, stream>>>(xt, Wb, bias, neigh, out);
}